// Round 11
// baseline (74.625 us; speedup 1.0000x reference)
//
#include <hip/hip_runtime.h>
#include <hip/hip_bf16.h>
#include <stdint.h>

#define IN_DIM  1024
#define LOW     128
#define OUT_DIM 1024
#define BATCH   8
#define SEQ     2048

typedef unsigned short u16;
typedef short bf16x8 __attribute__((ext_vector_type(8)));
typedef unsigned short u16x4 __attribute__((ext_vector_type(4)));
typedef float f32x4 __attribute__((ext_vector_type(4)));

__device__ __forceinline__ u16 f2bf(float f) {
    union { float f; uint32_t u; } v;
    v.f = f;
    uint32_t u = v.u;
    return (u16)((u + 0x7fffu + ((u >> 16) & 1u)) >> 16);
}

// ---------------------------------------------------------------------------
// gen_w v10: merged D+U, XCD-swizzled, max-TLP reg-burst (v8 verified math).
//   D (swz<1024):  DgT[b][l][d] = dot(Dm[d*128+l][:], k[b][:])
//   U (swz>=1024): UgT[b][o][l] = dot(Um[l*1024+o][:], k[b][:])
// grid 2048 x 256thr. Bijective XCD swizzle swz=(bid&7)*256+(bid>>3):
// consecutive-memory blocks share an XCD; XCDs 0-3 stream Dm while 4-7
// stream Um (two concurrent streams). Block = 128 p-rows (16 m x 8 n),
// 4 waves x 2 tiles of 16 rows; 16x16B loads/thread burst-issued before
// compute (~100 VGPR -> more resident waves than v8's 32-load version).
// MFMA: A from regs (f2bf), B = bf16(k) 16 VGPRs, C/D col=lane&15 (=batch),
// row=hi*4+j  [verified R5/R7, absmax 0.0195]. tb 2KB, one barrier, flush.
// ---------------------------------------------------------------------------
__global__ __launch_bounds__(256) void gen_w(const float* __restrict__ Dm,
                                             const float* __restrict__ Um,
                                             const float* __restrict__ kv,
                                             u16* __restrict__ DgT,
                                             u16* __restrict__ UgT) {
    __shared__ u16 tb[8 * 8 * 16];   // [b][n-local 8][m-local 16], 2 KB

    int t = threadIdx.x;
    int bid = blockIdx.x;
    int swz = ((bid & 7) << 8) | (bid >> 3);   // bijective: 2048 = 8*256
    bool isU = swz >= 1024;
    int rb = swz & 1023;
    const float* src = isU ? Um : Dm;
    u16* outp = isU ? UgT : DgT;
    int NTOT = isU ? 1024 : 128;   // p = m*NTOT + n
    int MTOT = isU ? 128 : 1024;   // output contiguous-run dim
    int sh = isU ? 7 : 4;
    int m0 = (rb >> sh) * 16;
    int n0 = (rb & ((1 << sh) - 1)) * 8;

    int lane = t & 63, w = t >> 6;
    int lr = lane & 15;            // A-row / C-col (batch)
    int hi = lane >> 4;            // k-group / C row-group

    // B-fragments: bf16(k[batch=lr][k]), k = ks*32 + hi*8 + j; rows 8..15 = 0
    bf16x8 bfrag[4];
#pragma unroll
    for (int ks = 0; ks < 4; ++ks)
#pragma unroll
        for (int j = 0; j < 8; ++j) {
            float kvf = (lr < 8) ? kv[lr * LOW + ks * 32 + hi * 8 + j] : 0.f;
            bfrag[ks][j] = (short)f2bf(kvf);
        }

    // wave w owns m-locals 4w..4w+3 (tiles i=0,1; tile = 2 m x 8 n rows)
    const float* ab0 = src +
        ((size_t)(m0 + w * 4 + (lr >> 3)) * NTOT + n0 + (lr & 7)) * 128 + hi * 8;
    const float* ab1 = ab0 + (size_t)2 * NTOT * 128;

    // burst-issue all 16 loads (both tiles) before any compute
    f32x4 L0[8], L1[8];
#pragma unroll
    for (int ks = 0; ks < 4; ++ks) {
        L0[2 * ks]     = *(const f32x4*)(ab0 + ks * 32);
        L0[2 * ks + 1] = *(const f32x4*)(ab0 + ks * 32 + 4);
    }
#pragma unroll
    for (int ks = 0; ks < 4; ++ks) {
        L1[2 * ks]     = *(const f32x4*)(ab1 + ks * 32);
        L1[2 * ks + 1] = *(const f32x4*)(ab1 + ks * 32 + 4);
    }

#define COMPUTE(Lb, i)                                                        \
    {                                                                         \
        f32x4 acc = (f32x4){0.f, 0.f, 0.f, 0.f};                              \
        _Pragma("unroll")                                                     \
        for (int ks = 0; ks < 4; ++ks) {                                      \
            f32x4 v0 = Lb[2 * ks], v1 = Lb[2 * ks + 1];                       \
            bf16x8 afr;                                                       \
            afr[0] = (short)f2bf(v0.x); afr[1] = (short)f2bf(v0.y);           \
            afr[2] = (short)f2bf(v0.z); afr[3] = (short)f2bf(v0.w);           \
            afr[4] = (short)f2bf(v1.x); afr[5] = (short)f2bf(v1.y);           \
            afr[6] = (short)f2bf(v1.z); afr[7] = (short)f2bf(v1.w);           \
            acc = __builtin_amdgcn_mfma_f32_16x16x32_bf16(afr, bfrag[ks],     \
                                                          acc, 0, 0, 0);      \
        }                                                                     \
        if (lr < 8) {                                                         \
            _Pragma("unroll")                                                 \
            for (int j = 0; j < 4; ++j) {                                     \
                int r = hi * 4 + j;                   /* tile row 0..15 */    \
                int mm = w * 4 + (i) * 2 + (r >> 3);  /* m-local 0..15 */     \
                tb[lr * 128 + (r & 7) * 16 + mm] = f2bf(acc[j]);              \
            }                                                                 \
        }                                                                     \
    }

    COMPUTE(L0, 0)
    COMPUTE(L1, 1)
#undef COMPUTE

    __syncthreads();   // tb visible

    // coalesced flush: 64 (b,n') pairs x 32B (16 m), 8B per thread
    int pair = t >> 2, q4 = t & 3;
    int bw = pair >> 3, np = pair & 7;
    u16x4 vv = *(const u16x4*)(tb + bw * 128 + np * 16 + q4 * 4);
    *(u16x4*)(outp + ((size_t)(bw * NTOT + n0 + np)) * MTOT + m0 + q4 * 4) = vv;
}

// ---------------------------------------------------------------------------
// fc1: h[b][s][l] = relu( sum_d x[b][s][d] * D[b][d][l] )  -> bf16
// tile: M=32 (s), N=128 (all l), K-loop 1024 step 64. grid = 8*64 = 512
// ---------------------------------------------------------------------------
__global__ __launch_bounds__(256) void fc1(const float* __restrict__ x,
                                           const u16* __restrict__ DgT,
                                           u16* __restrict__ h) {
    __shared__ u16 As[32][72];
    __shared__ u16 Bs[128][72];
    int t = threadIdx.x;
    int bid = blockIdx.x;
    int b = bid >> 6, st = bid & 63;
    int s0 = st * 32;
    const float* xb = x + ((size_t)b * SEQ + s0) * IN_DIM;
    const u16* Db = DgT + (size_t)b * LOW * IN_DIM;

    int w = t >> 6, lane = t & 63;
    int wm = w >> 1, wn = w & 1;
    int lr = lane & 15, hi = lane >> 4;

    f32x4 acc[4];
#pragma unroll
    for (int nf = 0; nf < 4; ++nf) acc[nf] = (f32x4){0.f, 0.f, 0.f, 0.f};

    int ar = t >> 3, ac = t & 7;
    int brt = t >> 3, bc = t & 7;

    for (int kt = 0; kt < IN_DIM / 64; ++kt) {
        int k0 = kt * 64;
#pragma unroll
        for (int i = 0; i < 2; ++i) {
            float4 v = *(const float4*)(xb + (size_t)ar * IN_DIM + k0 + ac * 4 + i * 32);
            u16x4 o;
            o.x = f2bf(v.x); o.y = f2bf(v.y); o.z = f2bf(v.z); o.w = f2bf(v.w);
            *(u16x4*)(&As[ar][ac * 4 + i * 32]) = o;
        }
#pragma unroll
        for (int i = 0; i < 4; ++i) {
            int row = brt + 32 * i;
            bf16x8 v = *(const bf16x8*)(Db + (size_t)row * IN_DIM + k0 + bc * 8);
            *(bf16x8*)(&Bs[row][bc * 8]) = v;
        }
        __syncthreads();
#pragma unroll
        for (int ks = 0; ks < 2; ++ks) {
            int kk = ks * 32 + hi * 8;
            bf16x8 af = *(const bf16x8*)(&As[wm * 16 + lr][kk]);
#pragma unroll
            for (int nf = 0; nf < 4; ++nf) {
                bf16x8 bf = *(const bf16x8*)(&Bs[wn * 64 + nf * 16 + lr][kk]);
                acc[nf] = __builtin_amdgcn_mfma_f32_16x16x32_bf16(af, bf, acc[nf], 0, 0, 0);
            }
        }
        __syncthreads();
    }
    u16* hb = h + ((size_t)b * SEQ + s0) * LOW;
#pragma unroll
    for (int nf = 0; nf < 4; ++nf) {
        int col = wn * 64 + nf * 16 + lr;
#pragma unroll
        for (int j = 0; j < 4; ++j) {
            int rrow = wm * 16 + hi * 4 + j;
            hb[(size_t)rrow * LOW + col] = f2bf(fmaxf(acc[nf][j], 0.f));
        }
    }
}

// ---------------------------------------------------------------------------
// fc2: out[b][s][o] = sum_l h[b][s][l] * U[b][l][o]   (f32 out)
// tile: 128x128, K=128 staged once. grid = 8*16*8 = 1024
// ---------------------------------------------------------------------------
__global__ __launch_bounds__(256) void fc2(const u16* __restrict__ h,
                                           const u16* __restrict__ UgT,
                                           float* __restrict__ out) {
    __shared__ u16 As[128 * 128];
    __shared__ u16 Bs[128 * 128];
    int t = threadIdx.x;
    int bid = blockIdx.x;
    int b = bid >> 7, st = (bid >> 3) & 15, ot = bid & 7;
    int s0 = st * 128, o0 = ot * 128;
    const u16* hb = h + ((size_t)b * SEQ + s0) * LOW;
    const u16* Ub = UgT + ((size_t)b * OUT_DIM + o0) * LOW;

#pragma unroll
    for (int i = 0; i < 8; ++i) {
        int ch = i * 256 + t;
        int row = ch >> 4, c = ch & 15;
        int swc = c ^ (row & 7);
        *(bf16x8*)(As + row * 128 + swc * 8) = *(const bf16x8*)(hb + (size_t)ch * 8);
        *(bf16x8*)(Bs + row * 128 + swc * 8) = *(const bf16x8*)(Ub + (size_t)ch * 8);
    }
    __syncthreads();

    int w = t >> 6, lane = t & 63;
    int wm = w >> 1, wn = w & 1;
    int lr = lane & 15, lkc = (lane >> 4);

    f32x4 acc[4][4];
#pragma unroll
    for (int mf = 0; mf < 4; ++mf)
#pragma unroll
        for (int nf = 0; nf < 4; ++nf)
            acc[mf][nf] = (f32x4){0.f, 0.f, 0.f, 0.f};

#pragma unroll
    for (int ks = 0; ks < 4; ++ks) {
        bf16x8 af[4], bfr[4];
#pragma unroll
        for (int mf = 0; mf < 4; ++mf) {
            int row = wm * 64 + mf * 16 + lr;
            int swc = (ks * 4 + lkc) ^ (row & 7);
            af[mf] = *(const bf16x8*)(As + row * 128 + swc * 8);
        }
#pragma unroll
        for (int nf = 0; nf < 4; ++nf) {
            int row = wn * 64 + nf * 16 + lr;
            int swc = (ks * 4 + lkc) ^ (row & 7);
            bfr[nf] = *(const bf16x8*)(Bs + row * 128 + swc * 8);
        }
#pragma unroll
        for (int mf = 0; mf < 4; ++mf)
#pragma unroll
            for (int nf = 0; nf < 4; ++nf)
                acc[mf][nf] = __builtin_amdgcn_mfma_f32_16x16x32_bf16(
                    af[mf], bfr[nf], acc[mf][nf], 0, 0, 0);
    }

    float* ob = out + ((size_t)b * SEQ + s0) * OUT_DIM + o0;
#pragma unroll
    for (int mf = 0; mf < 4; ++mf)
#pragma unroll
        for (int nf = 0; nf < 4; ++nf) {
            int col = wn * 64 + nf * 16 + lr;
#pragma unroll
            for (int j = 0; j < 4; ++j) {
                int rrow = wm * 64 + mf * 16 + (lane >> 4) * 4 + j;
                ob[(size_t)rrow * OUT_DIM + col] = acc[mf][nf][j];
            }
        }
}

extern "C" void kernel_launch(void* const* d_in, const int* in_sizes, int n_in,
                              void* d_out, int out_size, void* d_ws, size_t ws_size,
                              hipStream_t stream) {
    const float* x  = (const float*)d_in[0];
    const float* kv = (const float*)d_in[1];
    const float* Dm = (const float*)d_in[2];
    const float* Um = (const float*)d_in[3];
    float* out = (float*)d_out;

    u16* DgT  = (u16*)d_ws;                                   // 2 MB
    u16* UgT  = DgT + (size_t)BATCH * LOW * IN_DIM;           // 2 MB
    u16* hbuf = UgT + (size_t)BATCH * OUT_DIM * LOW;          // 4 MB

    gen_w<<<dim3(2048), dim3(256), 0, stream>>>(Dm, Um, kv, DgT, UgT);
    fc1<<<dim3(512), dim3(256), 0, stream>>>(x, DgT, hbuf);
    fc2<<<dim3(1024), dim3(256), 0, stream>>>(hbuf, UgT, out);
}

// Round 12
// 63.442 us; speedup vs baseline: 1.1763x; 1.1763x over previous
//
#include <hip/hip_runtime.h>
#include <hip/hip_bf16.h>
#include <stdint.h>

#define IN_DIM  1024
#define LOW     128
#define OUT_DIM 1024
#define BATCH   8
#define SEQ     2048

typedef unsigned short u16;
typedef short bf16x8 __attribute__((ext_vector_type(8)));
typedef unsigned short u16x4 __attribute__((ext_vector_type(4)));
typedef float f32x4 __attribute__((ext_vector_type(4)));

__device__ __forceinline__ u16 f2bf(float f) {
    union { float f; uint32_t u; } v;
    v.f = f;
    uint32_t u = v.u;
    return (u16)((u + 0x7fffu + ((u >> 16) & 1u)) >> 16);
}

// ---------------------------------------------------------------------------
// gen_w v6 (R7 best config, verbatim): MFMA fed directly from global.
//   D half (bid<512):  DgT[b][l][d] = dot(Dm[d*128+l][:], k[b][:])
//   U half (bid>=512): UgT[b][o][l] = dot(Um[l*1024+o][:], k[b][:])
// Empirical: ~50us = ~2.5 TB/s pure read — at the measured read-path cap
// (7 structures within 6%; co-scheduled dual-stream null => machine cap).
// ---------------------------------------------------------------------------
__global__ __launch_bounds__(256) void gen_w(const float* __restrict__ Dm,
                                             const float* __restrict__ Um,
                                             const float* __restrict__ kv,
                                             u16* __restrict__ DgT,
                                             u16* __restrict__ UgT) {
    __shared__ u16 tb[8 * 8 * 32];   // [b][n-local 8][m-local 32], 4 KB

    int t = threadIdx.x;
    int bid = blockIdx.x;
    bool isU = bid >= 512;
    int rb = isU ? (bid - 512) : bid;
    const float* src = isU ? Um : Dm;
    u16* outp = isU ? UgT : DgT;
    int NTOT = isU ? 1024 : 128;   // p = m*NTOT + n
    int MTOT = isU ? 128 : 1024;   // output contiguous-run dim
    int sh = isU ? 7 : 4;
    int m0 = (rb >> sh) * 32;
    int n0 = (rb & ((1 << sh) - 1)) * 8;

    int lane = t & 63, w = t >> 6;
    int lr = lane & 15;            // A-row / C-col (batch) index
    int hi = lane >> 4;            // k-group / C row-group

    bf16x8 bfrag[4];
#pragma unroll
    for (int ks = 0; ks < 4; ++ks)
#pragma unroll
        for (int j = 0; j < 8; ++j) {
            float kvf = (lr < 8) ? kv[lr * LOW + ks * 32 + hi * 8 + j] : 0.f;
            bfrag[ks][j] = (short)f2bf(kvf);
        }

    const float* abase = src +
        ((size_t)(m0 + w * 8 + (lr >> 3)) * NTOT + n0 + (lr & 7)) * 128 + hi * 8;
    size_t tstep = (size_t)2 * NTOT * 128;

#define ISSUE(Lb, tau)                                                        \
    {                                                                         \
        const float* rp = abase + (size_t)(tau) * tstep;                      \
        _Pragma("unroll")                                                     \
        for (int ks = 0; ks < 4; ++ks) {                                      \
            Lb[2 * ks]     = *(const f32x4*)(rp + ks * 32);                   \
            Lb[2 * ks + 1] = *(const f32x4*)(rp + ks * 32 + 4);               \
        }                                                                     \
    }

#define COMPUTE(Lb, tau)                                                      \
    {                                                                         \
        f32x4 acc = (f32x4){0.f, 0.f, 0.f, 0.f};                              \
        _Pragma("unroll")                                                     \
        for (int ks = 0; ks < 4; ++ks) {                                      \
            f32x4 v0 = Lb[2 * ks], v1 = Lb[2 * ks + 1];                       \
            bf16x8 afr;                                                       \
            afr[0] = (short)f2bf(v0.x); afr[1] = (short)f2bf(v0.y);           \
            afr[2] = (short)f2bf(v0.z); afr[3] = (short)f2bf(v0.w);           \
            afr[4] = (short)f2bf(v1.x); afr[5] = (short)f2bf(v1.y);           \
            afr[6] = (short)f2bf(v1.z); afr[7] = (short)f2bf(v1.w);           \
            acc = __builtin_amdgcn_mfma_f32_16x16x32_bf16(afr, bfrag[ks],     \
                                                          acc, 0, 0, 0);      \
        }                                                                     \
        if (lr < 8) {                                                         \
            _Pragma("unroll")                                                 \
            for (int j = 0; j < 4; ++j) {                                     \
                int r = hi * 4 + j;                                           \
                int mm = w * 8 + (tau) * 2 + (r >> 3);                        \
                tb[lr * 256 + (r & 7) * 32 + mm] = f2bf(acc[j]);              \
            }                                                                 \
        }                                                                     \
    }

    f32x4 LA[8], LB[8];
    ISSUE(LA, 0)
    ISSUE(LB, 1)
    COMPUTE(LA, 0)
    ISSUE(LA, 2)
    COMPUTE(LB, 1)
    ISSUE(LB, 3)
    COMPUTE(LA, 2)
    COMPUTE(LB, 3)
#undef ISSUE
#undef COMPUTE

    __syncthreads();

    int c64 = t >> 2, q4 = t & 3;
    int bw = c64 >> 3, np = c64 & 7;
    bf16x8 v = *(const bf16x8*)(tb + bw * 256 + np * 32 + q4 * 8);
    *(bf16x8*)(outp + ((size_t)(bw * NTOT + n0 + np)) * MTOT + m0 + q4 * 8) = v;
}

// ---------------------------------------------------------------------------
// fc12: FUSED fc1+fc2. h never leaves LDS (saves the h round-trip and one
// dispatch gap).  out[b][s][o] = relu(x[b][s][:]@D[b])[l] @ U[b][l][o].
// Block = (b, 32 s-rows). XCD affinity: b = bid&7 -> all blocks of batch b
// on one XCD -> U[b] (256KB) stays L2-hot while re-read 64x.
// Phase 1 (verbatim fc1 body): K-loop over 1024, MFMA -> acc, relu -> bf16
//   -> hs (fc2-A swizzled layout: chunk c^=(row&7)).
// Phase 2 (verbatim fc2 patterns, M=32): 8 o-chunks of 128; stage U-chunk
//   swizzled, ah from hs (loaded once), 16 MFMA/chunk, f32 stores (64B runs).
// LDS: As 4.5KB + Bs 18KB + hs 8KB + Us 32KB = 62.5KB -> 2 blocks/CU.
// ---------------------------------------------------------------------------
__global__ __launch_bounds__(256) void fc12(const float* __restrict__ x,
                                            const u16* __restrict__ DgT,
                                            const u16* __restrict__ UgT,
                                            float* __restrict__ out) {
    __shared__ u16 As[32][72];
    __shared__ u16 Bs[128][72];
    __shared__ u16 hs[32 * 128];     // h tile, swizzled (chunk ^ row&7)
    __shared__ u16 Us[128 * 128];    // U o-chunk, swizzled

    int t = threadIdx.x;
    int bid = blockIdx.x;
    int b = bid & 7, st = bid >> 3;          // XCD affinity on b
    int s0 = st * 32;
    const float* xb = x + ((size_t)b * SEQ + s0) * IN_DIM;
    const u16* Db = DgT + (size_t)b * LOW * IN_DIM;

    int w = t >> 6, lane = t & 63;
    int wm = w >> 1, wn = w & 1;
    int lr = lane & 15, hi = lane >> 4;

    // ---------------- phase 1: h = relu(x @ D)  [fc1 verbatim] -------------
    f32x4 acc[4];
#pragma unroll
    for (int nf = 0; nf < 4; ++nf) acc[nf] = (f32x4){0.f, 0.f, 0.f, 0.f};

    int ar = t >> 3, ac = t & 7;
    int brt = t >> 3, bc = t & 7;

    for (int kt = 0; kt < IN_DIM / 64; ++kt) {
        int k0 = kt * 64;
#pragma unroll
        for (int i = 0; i < 2; ++i) {
            float4 v = *(const float4*)(xb + (size_t)ar * IN_DIM + k0 + ac * 4 + i * 32);
            u16x4 o;
            o.x = f2bf(v.x); o.y = f2bf(v.y); o.z = f2bf(v.z); o.w = f2bf(v.w);
            *(u16x4*)(&As[ar][ac * 4 + i * 32]) = o;
        }
#pragma unroll
        for (int i = 0; i < 4; ++i) {
            int row = brt + 32 * i;
            bf16x8 v = *(const bf16x8*)(Db + (size_t)row * IN_DIM + k0 + bc * 8);
            *(bf16x8*)(&Bs[row][bc * 8]) = v;
        }
        __syncthreads();
#pragma unroll
        for (int ks = 0; ks < 2; ++ks) {
            int kk = ks * 32 + hi * 8;
            bf16x8 af = *(const bf16x8*)(&As[wm * 16 + lr][kk]);
#pragma unroll
            for (int nf = 0; nf < 4; ++nf) {
                bf16x8 bf = *(const bf16x8*)(&Bs[wn * 64 + nf * 16 + lr][kk]);
                acc[nf] = __builtin_amdgcn_mfma_f32_16x16x32_bf16(af, bf, acc[nf], 0, 0, 0);
            }
        }
        __syncthreads();
    }
    // relu -> bf16 -> hs (swizzled: 16B-chunk c ^= row&7; 2-way writes = free)
#pragma unroll
    for (int nf = 0; nf < 4; ++nf) {
        int col = wn * 64 + nf * 16 + lr;
        int c = col >> 3;
#pragma unroll
        for (int j = 0; j < 4; ++j) {
            int row = wm * 16 + hi * 4 + j;
            int swc = c ^ (row & 7);
            hs[row * 128 + swc * 8 + (col & 7)] = f2bf(fmaxf(acc[nf][j], 0.f));
        }
    }
    __syncthreads();

    // ---------------- phase 2: out = h @ U  [fc2 patterns, M=32] -----------
    // A-frags from hs: loaded once, persist across o-chunks
    bf16x8 ah[4];
    {
        int row = wm * 16 + lr;
#pragma unroll
        for (int ks = 0; ks < 4; ++ks) {
            int swc = (ks * 4 + hi) ^ (row & 7);
            ah[ks] = *(const bf16x8*)(hs + row * 128 + swc * 8);
        }
    }

    const u16* Ub = UgT + (size_t)b * OUT_DIM * LOW;
    float* ob = out + ((size_t)b * SEQ + s0) * OUT_DIM;

    for (int oc = 0; oc < 8; ++oc) {
        // stage U-chunk: rows o = oc*128+row, swizzled dest (fc2 verbatim)
#pragma unroll
        for (int i = 0; i < 8; ++i) {
            int ch = i * 256 + t;
            int row = ch >> 4, c = ch & 15;
            int swc = c ^ (row & 7);
            *(bf16x8*)(Us + row * 128 + swc * 8) =
                *(const bf16x8*)(Ub + (size_t)(oc * 128 + row) * 128 + c * 8);
        }
        __syncthreads();

        f32x4 acc2[4];
#pragma unroll
        for (int nf = 0; nf < 4; ++nf) acc2[nf] = (f32x4){0.f, 0.f, 0.f, 0.f};

#pragma unroll
        for (int ks = 0; ks < 4; ++ks) {
#pragma unroll
            for (int nf = 0; nf < 4; ++nf) {
                int row = wn * 64 + nf * 16 + lr;
                int swc = (ks * 4 + hi) ^ (row & 7);
                bf16x8 bfr = *(const bf16x8*)(Us + row * 128 + swc * 8);
                acc2[nf] = __builtin_amdgcn_mfma_f32_16x16x32_bf16(
                    ah[ks], bfr, acc2[nf], 0, 0, 0);
            }
        }

        // store: col o contiguous over lr -> 64B runs
#pragma unroll
        for (int nf = 0; nf < 4; ++nf) {
            int col = oc * 128 + wn * 64 + nf * 16 + lr;
#pragma unroll
            for (int j = 0; j < 4; ++j) {
                int row = wm * 16 + hi * 4 + j;
                ob[(size_t)row * OUT_DIM + col] = acc2[nf][j];
            }
        }
        __syncthreads();   // Us reads done before next stage
    }
}

extern "C" void kernel_launch(void* const* d_in, const int* in_sizes, int n_in,
                              void* d_out, int out_size, void* d_ws, size_t ws_size,
                              hipStream_t stream) {
    const float* x  = (const float*)d_in[0];
    const float* kv = (const float*)d_in[1];
    const float* Dm = (const float*)d_in[2];
    const float* Um = (const float*)d_in[3];
    float* out = (float*)d_out;

    u16* DgT  = (u16*)d_ws;                                   // 2 MB
    u16* UgT  = DgT + (size_t)BATCH * LOW * IN_DIM;           // 2 MB

    gen_w<<<dim3(1024), dim3(256), 0, stream>>>(Dm, Um, kv, DgT, UgT);
    fc12<<<dim3(512), dim3(256), 0, stream>>>(x, DgT, UgT, out);
}